// Round 1
// 285.815 us; speedup vs baseline: 1.2784x; 1.2784x over previous
//
#include <hip/hip_runtime.h>
#include <math.h>

#define B_   4096
#define S_   64
#define H_   128
#define N_   (B_*S_)

// ---- workspace float offsets ----
#define WS_WC    0        // [384][16]  combined obs->gi weights (padded f=16)
#define WS_BC    6144     // [384]      combined gi bias
#define WS_WAP   6528     // [128][16]  padded enc_air_w
#define WS_WQP   8576     // [128][128] wq * qln_w (fp32 copy)
#define WS_SQ    24960    // [128] row sums of wqp
#define WS_EQ    25088    // [128] wq@qln_b + bq
#define WS_KC    25216    // [128][4]  (wk*klnw)@enc_m_w
#define WS_EK1   25728    // [128] (wk*klnw)@enc_m_b
#define WS_SK    25856    // [128] rowsum(wk*klnw)
#define WS_EK2   25984    // [128] wk@kln_b + bk
#define WS_VC    26112    // [128][4]  wv@enc_m_w
#define WS_VB    26624    // [128] wv@enc_m_b + bv
#define WS_MV    26752    // [4] mean weights for keys_raw mean
#define WS_QQ    26756    // [16] 4x4 quadratic form for E[y^2]
#define WS_QLIN  26772    // [4]
#define WS_MBC   26776
#define WS_C0    26777
#define WS_PB    27392    // packed bf16 region (shorts): GA[0..4095], GC5[4096..8191], mm=2 mlp0 @32768, mm=3 mlp1 @49152
#define WS_WO2T  (WS_PB + 4096)   // fp32 [21][128] Wo2 transposed
#define WS_SROW  (WS_PB + 6784)   // fp32 [28]
#define WS_EROW  (WS_PB + 6812)   // fp32 [28]
#define WS_GB    60160    // gru packed bf16 B-frags: 65536 ushort (32768 floats)
#define WS_AIR   92928    // [N_][128] air_feat buffer

typedef __attribute__((ext_vector_type(8))) short bf16x8;
typedef __attribute__((ext_vector_type(4))) float f32x4;

__device__ __forceinline__ float dot4(float4 a, float4 b){
    return fmaf(a.x,b.x, fmaf(a.y,b.y, fmaf(a.z,b.z, a.w*b.w)));
}
__device__ __forceinline__ unsigned short f2bf(float f){   // RNE fp32->bf16
    union { float f; unsigned u; } v; v.f = f;
    unsigned r = v.u + 0x7FFF + ((v.u >> 16) & 1);
    return (unsigned short)(r >> 16);
}
__device__ __forceinline__ float bf2f(unsigned short u){
    union { unsigned u; float f; } v; v.u = ((unsigned)u) << 16;
    return v.f;
}

// ---------------- precompute folded weights + mlp bf16 B-frags ----------------
__global__ void precompute_kernel(
    const float* __restrict__ enc_air_w, const float* __restrict__ enc_air_b,
    const float* __restrict__ enc_m_w,  const float* __restrict__ enc_m_b,
    const float* __restrict__ gru_wih,  const float* __restrict__ gru_bih,
    const float* __restrict__ qln_w, const float* __restrict__ qln_b,
    const float* __restrict__ kln_w, const float* __restrict__ kln_b,
    const float* __restrict__ attn_in_w, const float* __restrict__ attn_in_b,
    const float* __restrict__ attn_out_w,
    const float* __restrict__ mlp0_w, const float* __restrict__ mlp1_w,
    float* __restrict__ ws)
{
    int i = blockIdx.x*blockDim.x + threadIdx.x;
    if (i < 6144) {                       // Wc[o][f] = sum_k wih[o][k]*Wa[k][f]
        int o = i>>4, f = i&15; float a = 0.f;
        if (f < 15) for (int k=0;k<128;k++) a = fmaf(gru_wih[o*128+k], enc_air_w[k*15+f], a);
        ws[WS_WC+i] = a;
    } else if (i < 6528) {                // bc
        int o = i-6144; float a = gru_bih[o];
        for (int k=0;k<128;k++) a = fmaf(gru_wih[o*128+k], enc_air_b[k], a);
        ws[WS_BC+o] = a;
    } else if (i < 8576) {                // Wap padded
        int idx = i-6528; int j = idx>>4, f = idx&15;
        ws[WS_WAP+idx] = (f<15) ? enc_air_w[j*15+f] : 0.f;
    } else if (i < 24960) {               // wqp (fp32 copy)
        int idx = i-8576; int o = idx>>7, j = idx&127;
        ws[WS_WQP+idx] = attn_in_w[o*128+j]*qln_w[j];
    } else if (i < 25088) {               // sq
        int o = i-24960; float a=0.f;
        for (int j=0;j<128;j++) a = fmaf(attn_in_w[o*128+j], qln_w[j], a);
        ws[WS_SQ+o]=a;
    } else if (i < 25216) {               // eq
        int o = i-25088; float a = attn_in_b[o];
        for (int j=0;j<128;j++) a = fmaf(attn_in_w[o*128+j], qln_b[j], a);
        ws[WS_EQ+o]=a;
    } else if (i < 25728) {               // Kc
        int idx = i-25216; int o = idx>>2, f = idx&3; float a=0.f;
        for (int j=0;j<128;j++) a = fmaf(attn_in_w[(128+o)*128+j]*kln_w[j], enc_m_w[j*4+f], a);
        ws[WS_KC+idx]=a;
    } else if (i < 25856) {               // ek1
        int o = i-25728; float a=0.f;
        for (int j=0;j<128;j++) a = fmaf(attn_in_w[(128+o)*128+j]*kln_w[j], enc_m_b[j], a);
        ws[WS_EK1+o]=a;
    } else if (i < 25984) {               // sk
        int o = i-25856; float a=0.f;
        for (int j=0;j<128;j++) a = fmaf(attn_in_w[(128+o)*128+j], kln_w[j], a);
        ws[WS_SK+o]=a;
    } else if (i < 26112) {               // ek2
        int o = i-25984; float a = attn_in_b[128+o];
        for (int j=0;j<128;j++) a = fmaf(attn_in_w[(128+o)*128+j], kln_b[j], a);
        ws[WS_EK2+o]=a;
    } else if (i < 26624) {               // Vc
        int idx = i-26112; int o = idx>>2, f = idx&3; float a=0.f;
        for (int j=0;j<128;j++) a = fmaf(attn_in_w[(256+o)*128+j], enc_m_w[j*4+f], a);
        ws[WS_VC+idx]=a;
    } else if (i < 26752) {               // vb
        int o = i-26624; float a = attn_in_b[256+o];
        for (int j=0;j<128;j++) a = fmaf(attn_in_w[(256+o)*128+j], enc_m_b[j], a);
        ws[WS_VB+o]=a;
    } else if (i < 26756) {               // Mv
        int f = i-26752; float a=0.f;
        for (int j=0;j<128;j++) a += enc_m_w[j*4+f];
        ws[WS_MV+f]=a*(1.f/128.f);
    } else if (i < 26772) {               // QQ
        int idx = i-26756; int a4 = idx>>2, b4 = idx&3; float a=0.f;
        for (int j=0;j<128;j++) a = fmaf(enc_m_w[j*4+a4], enc_m_w[j*4+b4], a);
        ws[WS_QQ+idx]=a*(1.f/128.f);
    } else if (i < 26776) {               // qlin
        int f = i-26772; float a=0.f;
        for (int j=0;j<128;j++) a = fmaf(enc_m_b[j], enc_m_w[j*4+f], a);
        ws[WS_QLIN+f]=a*(2.f/128.f);
    } else if (i == 26776) {
        float a=0.f; for (int j=0;j<128;j++) a += enc_m_b[j];
        ws[WS_MBC]=a*(1.f/128.f);
    } else if (i == 26777) {
        float a=0.f; for (int j=0;j<128;j++) a = fmaf(enc_m_b[j], enc_m_b[j], a);
        ws[WS_C0]=a*(1.f/128.f);
    } else if (i >= 32768 && i < 98304) {
        // mlp bf16 B-frags (mm=2: mlp0, mm=3: mlp1); mm=0/1 regions now repurposed
        int idx = i - 32768;              // 0..65535
        int mm = idx>>14;
        if (mm >= 2) {
            int i8 = idx & 7, l = (idx>>3)&63, p = (idx>>9)&3, wv = (idx>>11)&7;
            int n = 16*wv + (l&15);
            int k = 32*p + ((l>>4)<<3) + i8;
            float v = (mm==2) ? mlp0_w[n*128+k] : mlp1_w[n*128+k];
            ((unsigned short*)(ws+WS_PB))[idx] = f2bf(v);
        }
    }
}

// ---------------- pack GRU bf16 B-frags (after precompute: reads WS_WC/WS_WAP) ----
__global__ void pack_gru_kernel(const float* __restrict__ whh, float* __restrict__ ws)
{
    int idx = blockIdx.x*blockDim.x + threadIdx.x;   // [0, 65536)
    int i8 = idx&7, l=(idx>>3)&63, w=(idx>>9)&7, f=idx>>12;
    int n = 16*w + (l&15);
    int k = ((l>>4)<<3) + i8;       // 0..31 within chunk
    float v = 0.f;
    if (f < 5) {
        int kk = f*32 + k;
        if (kk < 128) v = whh[n*128 + kk];
        else { int kl = kk-128; if (kl<16) v = ws[WS_WC + n*16 + kl]; }
    } else if (f < 10) {
        int kk = (f-5)*32 + k;
        if (kk < 128) v = whh[(128+n)*128 + kk];
        else { int kl = kk-128; if (kl<16) v = ws[WS_WC + (128+n)*16 + kl]; }
    } else if (f < 14) {
        int kk = (f-10)*32 + k;
        v = whh[(256+n)*128 + kk];
    } else if (f == 14) {
        if (k < 16) v = ws[WS_WC + (256+n)*16 + k];
    } else {
        if (k < 16) v = ws[WS_WAP + n*16 + k];
    }
    ((unsigned short*)(ws+WS_GB))[idx] = f2bf(v);
}

// ---------------- pack2: GA (score projections), Srow/Erow, Wo2T ----------------
// GA[r][k], r = h*7+u: u<4 -> Kc[:,u] proj; u=4 ek1; u=5 sk; u=6 ek2, folded through wqp.
__global__ void pack2_kernel(const float* __restrict__ wo, const float* __restrict__ bo,
                             float* __restrict__ ws)
{
    int i = blockIdx.x*blockDim.x + threadIdx.x;   // 27*256 = 6912
    if (i < 4096) {                                // GA packed bf16 (2 col-tiles x 4 ksteps)
        int i8=i&7, l=(i>>3)&63, p=(i>>9)&3, ct=(i>>11)&1;
        int r = 16*ct + (l&15);
        int k = 32*p + ((l>>4)<<3) + i8;
        float v = 0.f;
        if (r < 28){
            int h = r/7, u = r - h*7;
            float a = 0.f;
            for (int d5=0; d5<32; d5++){
                int d = h*32 + d5;
                float c = (u<4) ? ws[WS_KC + d*4 + u]
                        : (u==4) ? ws[WS_EK1 + d]
                        : (u==5) ? ws[WS_SK + d]
                        :          ws[WS_EK2 + d];
                a = fmaf(c, ws[WS_WQP + d*128 + k], a);
            }
            v = a;
        }
        ((unsigned short*)(ws+WS_PB))[i] = f2bf(v);
    } else if (i < 4152) {                         // Srow (sum_j GA = c.sq) / Erow (c.eq)
        int j = i - 4096; int r = j % 28; int era = j / 28;
        int h = r/7, u = r - h*7;
        float a = 0.f;
        for (int d5=0; d5<32; d5++){
            int d = h*32 + d5;
            float c = (u<4) ? ws[WS_KC + d*4 + u]
                    : (u==4) ? ws[WS_EK1 + d]
                    : (u==5) ? ws[WS_SK + d]
                    :          ws[WS_EK2 + d];
            a = fmaf(c, ws[(era ? WS_EQ : WS_SQ) + d], a);
        }
        ws[(era ? WS_EROW : WS_SROW) + r] = a;
    } else if (i >= 4224 && i < 6912) {            // Wo2T[c][o]: attn_out_w folded with Vc/vb; c=20 -> bo
        int j = i - 4224; int c = j>>7, o = j&127;
        float a;
        if (c == 20) a = bo[o];
        else {
            int h = c/5, u = c - h*5;
            a = 0.f;
            for (int d5=0; d5<32; d5++){
                int d = h*32 + d5;
                float cv = (u<4) ? ws[WS_VC + d*4 + u] : ws[WS_VB + d];
                a = fmaf(wo[o*128 + d], cv, a);
            }
        }
        ws[WS_WO2T + c*128 + o] = a;
    }
}

// ---------------- pack3: GC5 = mlp0_w @ Wo2 (k-step 4 of the fused mlp0 GEMM) -----
__global__ void pack3_kernel(const float* __restrict__ mlp0_w, float* __restrict__ ws)
{
    int i = blockIdx.x*blockDim.x + threadIdx.x;   // 4096
    int i8=i&7, l=(i>>3)&63, w=(i>>9)&7;
    int n = 16*w + (l&15);
    int c = ((l>>4)<<3) + i8;                      // 0..31 (cols 128..159 of Wc)
    float v = 0.f;
    if (c < 21){
        float a = 0.f;
        const float* wo2 = ws + WS_WO2T + c*128;
        for (int o=0;o<128;o++) a = fmaf(mlp0_w[n*128+o], wo2[o], a);
        v = a;
    }
    ((unsigned short*)(ws+WS_PB))[4096 + i] = f2bf(v);
}

// ---------------- Kernel A: GRU via bf16 MFMA (unchanged) ----------------
__global__ __launch_bounds__(512) __attribute__((amdgpu_waves_per_eu(2, 2)))
void gru_kernel(
    const float* __restrict__ obs, const float* __restrict__ h0,
    const float* __restrict__ bhh, const float* __restrict__ ba,
    const float* __restrict__ ws,
    float* __restrict__ air, float* __restrict__ out)
{
    __shared__ __align__(16) unsigned short Abf[2][16*168];  // [token][k], pitch 168 shorts
    __shared__ float h32[2][16*132];
    __shared__ float air_s[16*132];

    const int t = threadIdx.x;
    const int w = t>>6;          // wave 0..7
    const int l = t&63;
    const int quad = l>>4;
    const int col  = l&15;
    const int jj   = 16*w + col; // output column j
    const int row0 = blockIdx.x*16;

    const unsigned short* gb = (const unsigned short*)(ws + WS_GB);
    bf16x8 bf[16];
    #pragma unroll
    for (int f=0; f<16; f++) bf[f] = *(const bf16x8*)&gb[(f*8 + w)*512 + l*8];

    const float bcrt = ws[WS_BC+jj]     + bhh[jj];
    const float bczt = ws[WS_BC+128+jj] + bhh[128+jj];
    const float bcn  = ws[WS_BC+256+jj];
    const float bhn  = bhh[256+jj];
    const float baj  = ba[jj];

    {
        int rr = t>>5, c0 = (t&31)*4;
        float4 hv = *(const float4*)&h0[(size_t)(row0+rr)*128 + c0];
        *(float4*)&h32[0][rr*132 + c0] = hv;
        unsigned long long pk = (unsigned long long)f2bf(hv.x)
              | ((unsigned long long)f2bf(hv.y)<<16)
              | ((unsigned long long)f2bf(hv.z)<<32)
              | ((unsigned long long)f2bf(hv.w)<<48);
        *(unsigned long long*)&Abf[0][rr*168 + c0] = pk;
    }
    if (t < 256){
        int tok = t>>4, c = t&15;
        float o = (c<15) ? obs[((size_t)(row0+tok)*64 + 0)*15 + c] : 0.f;
        Abf[0][tok*168 + 128 + c] = f2bf(o);
    } else {
        int idx = t-256; int tok = idx>>4, kk = 144 + (idx&15);
        Abf[0][tok*168 + kk] = 0;
        Abf[1][tok*168 + kk] = 0;
    }
    __syncthreads();

    for (int s=0; s<64; s++){
        const unsigned short* Ac = Abf[s&1];
        unsigned short*       An = Abf[(s+1)&1];
        const float* hc = h32[s&1];
        float*       hx = h32[(s+1)&1];

        float obs_pf = 0.f;
        if (t < 256){
            int tok = t>>4, c = t&15;
            int sn = (s<63) ? s+1 : s;
            obs_pf = (c<15) ? obs[((size_t)(row0+tok)*64 + sn)*15 + c] : 0.f;
        }

        bf16x8 a0 = *(const bf16x8*)&Ac[col*168 +   0 + quad*8];
        bf16x8 a1 = *(const bf16x8*)&Ac[col*168 +  32 + quad*8];
        bf16x8 a2 = *(const bf16x8*)&Ac[col*168 +  64 + quad*8];
        bf16x8 a3 = *(const bf16x8*)&Ac[col*168 +  96 + quad*8];
        bf16x8 a4 = *(const bf16x8*)&Ac[col*168 + 128 + quad*8];

        f32x4 aR = {0.f,0.f,0.f,0.f};
        f32x4 aZ = {0.f,0.f,0.f,0.f};
        f32x4 aN = {0.f,0.f,0.f,0.f};
        f32x4 aG = {0.f,0.f,0.f,0.f};
        f32x4 aE = {0.f,0.f,0.f,0.f};
        aR = __builtin_amdgcn_mfma_f32_16x16x32_bf16(a0, bf[0],  aR, 0,0,0);
        aR = __builtin_amdgcn_mfma_f32_16x16x32_bf16(a1, bf[1],  aR, 0,0,0);
        aR = __builtin_amdgcn_mfma_f32_16x16x32_bf16(a2, bf[2],  aR, 0,0,0);
        aR = __builtin_amdgcn_mfma_f32_16x16x32_bf16(a3, bf[3],  aR, 0,0,0);
        aR = __builtin_amdgcn_mfma_f32_16x16x32_bf16(a4, bf[4],  aR, 0,0,0);
        aZ = __builtin_amdgcn_mfma_f32_16x16x32_bf16(a0, bf[5],  aZ, 0,0,0);
        aZ = __builtin_amdgcn_mfma_f32_16x16x32_bf16(a1, bf[6],  aZ, 0,0,0);
        aZ = __builtin_amdgcn_mfma_f32_16x16x32_bf16(a2, bf[7],  aZ, 0,0,0);
        aZ = __builtin_amdgcn_mfma_f32_16x16x32_bf16(a3, bf[8],  aZ, 0,0,0);
        aZ = __builtin_amdgcn_mfma_f32_16x16x32_bf16(a4, bf[9],  aZ, 0,0,0);
        aN = __builtin_amdgcn_mfma_f32_16x16x32_bf16(a0, bf[10], aN, 0,0,0);
        aN = __builtin_amdgcn_mfma_f32_16x16x32_bf16(a1, bf[11], aN, 0,0,0);
        aN = __builtin_amdgcn_mfma_f32_16x16x32_bf16(a2, bf[12], aN, 0,0,0);
        aN = __builtin_amdgcn_mfma_f32_16x16x32_bf16(a3, bf[13], aN, 0,0,0);
        aG = __builtin_amdgcn_mfma_f32_16x16x32_bf16(a4, bf[14], aG, 0,0,0);
        aE = __builtin_amdgcn_mfma_f32_16x16x32_bf16(a4, bf[15], aE, 0,0,0);

        #pragma unroll
        for (int reg=0; reg<4; reg++){
            int tok = quad*4 + reg;
            float rg = 1.f/(1.f+__expf(-(aR[reg] + bcrt)));
            float zg = 1.f/(1.f+__expf(-(aZ[reg] + bczt)));
            float nx = fmaf(rg, aN[reg] + bhn, aG[reg] + bcn);
            float e2 = __expf(2.f*nx);
            float ng = 1.f - 2.f/(e2+1.f);            // tanh(nx)
            float hold = hc[tok*132 + jj];
            float hn = fmaf(zg, hold-ng, ng);         // (1-z)n + z*h
            hx[tok*132 + jj] = hn;
            An[tok*168 + jj] = f2bf(hn);
            air_s[tok*132 + jj] = hn + (aE[reg] + baj);
            if (s==63) out[(size_t)N_ + (size_t)(row0+tok)*128 + jj] = hn;
        }
        __syncthreads();   // bar_1

        {
            int rr = t>>5, c0 = (t&31)*4;
            float4 av = *(const float4*)&air_s[rr*132 + c0];
            *(float4*)&air[((size_t)(row0+rr)*64 + s)*128 + c0] = av;
        }
        if (t < 256){
            int tok = t>>4, c = t&15;
            An[tok*168 + 128 + c] = f2bf(obs_pf);
        }
        __syncthreads();   // bar_2
    }
}

// ---------------- Kernel B v2: attention + MLP, 64 tokens/block, folded GEMMs ----
// Phase 0: load X(air)->U_bf cols 0..127, LN stats, obs_m, k-LN stats/masks
// Phase 1: GEMM A  X @ GA^T[28x128]  -> praw (score projections, LN applied)
// Phase 2: scores + softmax -> Yc (mb[4],sab per head + indicator) -> U_bf cols 128..148
// Phase 3: GEMM C  [X|Yc](K=160) @ Wc^T -> leaky -> H1_bf   (attn_out+residual folded in)
// Phase 4: GEMM D  H1 @ mlp1^T -> leaky -> *fcw -> 16-lane reduce -> part
// Phase 5: 8-wave sum -> out
__global__ __launch_bounds__(512) void attnmlp_kernel(
    const float* __restrict__ obs,
    const float* __restrict__ ws,
    const float* __restrict__ b0, const float* __restrict__ b1,
    const float* __restrict__ fcw, const float* __restrict__ fcb,
    const float* __restrict__ air, float* __restrict__ out)
{
    __shared__ __align__(16) unsigned short U_bf[64*168];   // 21504 B, cols: 0..127 X, 128..147 Yc, 148 ind, 149..167 zero
    __shared__ __align__(16) unsigned short H1_bf[64*136];  // 17408 B
    __shared__ float praw[64*28];                           // 7168 B; reused as part[64][8] in phase 4/5
    __shared__ float obs_m[64][8];
    __shared__ float mu_s[64], rs_s[64];
    __shared__ float kmu_s[64][2], krs_s[64][2];
    __shared__ int   kmask_s[64][2];

    const int t = threadIdx.x;
    const int w = t>>6;
    const int l = t&63;
    const int quad = l>>4;
    const int col  = l&15;
    const int jj   = 16*w + col;
    const int n0 = blockIdx.x*64;

    const unsigned short* pb = (const unsigned short*)(ws + WS_PB);

    // ---- phase 0 ----
    {
        const int tok0 = t>>3, sub = t&7;
        const float* ap = &air[(size_t)(n0+tok0)*128 + sub*16];
        float sm = 0.f, s2 = 0.f;
        #pragma unroll
        for (int q4=0;q4<4;q4++){
            float4 xv = *(const float4*)&ap[q4*4];
            unsigned long long pk = (unsigned long long)f2bf(xv.x)
                  | ((unsigned long long)f2bf(xv.y)<<16)
                  | ((unsigned long long)f2bf(xv.z)<<32)
                  | ((unsigned long long)f2bf(xv.w)<<48);
            *(unsigned long long*)&U_bf[tok0*168 + sub*16 + q4*4] = pk;
            sm += xv.x+xv.y+xv.z+xv.w;
            s2 += fmaf(xv.x,xv.x, fmaf(xv.y,xv.y, fmaf(xv.z,xv.z, xv.w*xv.w)));
        }
        #pragma unroll
        for (int m=1;m<8;m<<=1){ sm += __shfl_xor(sm,m); s2 += __shfl_xor(s2,m); }
        if (sub==0){
            float mu = sm*(1.f/128.f);
            float var = s2*(1.f/128.f) - mu*mu;
            mu_s[tok0]=mu; rs_s[tok0]=rsqrtf(var+1e-5f);
        }
        if (sub<5){
            #pragma unroll
            for (int c=0;c<4;c++) U_bf[tok0*168 + 148 + sub*4 + c] = 0;
        }
        obs_m[tok0][sub] = obs[(size_t)(n0+tok0)*15 + sub];
    }
    if (t < 128){
        int rr = t>>1, mi = t&1;
        const float* mp = &obs[(size_t)(n0+rr)*15 + mi*4];
        float m0=mp[0], m1=mp[1], m2=mp[2], m3=mp[3];
        const float tol1 = 1e-8f + 1e-5f, tol0 = 1e-8f;
        kmask_s[rr][mi] = (fabsf(m0-1.f)<=tol1)&&(fabsf(m1)<=tol0)&&
                          (fabsf(m2-1.f)<=tol1)&&(fabsf(m3)<=tol0);
        float mv[4]={m0,m1,m2,m3};
        float mu = ws[WS_MBC];
        #pragma unroll
        for (int f=0;f<4;f++) mu = fmaf(ws[WS_MV+f], mv[f], mu);
        float e2 = ws[WS_C0];
        #pragma unroll
        for (int a4=0;a4<4;a4++){
            e2 = fmaf(ws[WS_QLIN+a4], mv[a4], e2);
            #pragma unroll
            for (int b4=0;b4<4;b4++) e2 = fmaf(ws[WS_QQ+a4*4+b4]*mv[a4], mv[b4], e2);
        }
        float var = e2 - mu*mu;
        kmu_s[rr][mi]=mu; krs_s[rr][mi]=rsqrtf(var+1e-5f);
    }
    __syncthreads();

    // ---- phase 1: GEMM A -> praw ----
    {
        const int tt = w>>1, ct = w&1;
        const int jA = ct*16 + col;
        f32x4 acc = {0.f,0.f,0.f,0.f};
        #pragma unroll
        for (int p=0;p<4;p++){
            bf16x8 a = *(const bf16x8*)&U_bf[(tt*16+col)*168 + p*32 + quad*8];
            bf16x8 b = *(const bf16x8*)&pb[((ct*4+p)*64 + l)*8];
            acc = __builtin_amdgcn_mfma_f32_16x16x32_bf16(a, b, acc, 0,0,0);
        }
        if (jA < 28){
            const float Sr = ws[WS_SROW + jA], Er = ws[WS_EROW + jA];
            #pragma unroll
            for (int reg=0;reg<4;reg++){
                int tok = tt*16 + quad*4 + reg;
                praw[tok*28 + jA] = fmaf(rs_s[tok], acc[reg] - mu_s[tok]*Sr, Er);
            }
        }
    }
    __syncthreads();

    // ---- phase 2: scores + softmax -> Yc ----
    if (t < 256){
        const int tok = t>>2, h = t&3;
        const float* pr = &praw[tok*28 + h*7];
        const float T0=pr[0],T1=pr[1],T2=pr[2],T3=pr[3],Pa=pr[4],Pb=pr[5],Pc=pr[6];
        const float4 m0v = *(const float4*)&obs_m[tok][0];
        const float4 m1v = *(const float4*)&obs_m[tok][4];
        const float scale = 0.17677669529663687f;  // 1/sqrt(32)
        float d0 = fmaf(T0,m0v.x, fmaf(T1,m0v.y, fmaf(T2,m0v.z, fmaf(T3,m0v.w, Pa))));
        float d1 = fmaf(T0,m1v.x, fmaf(T1,m1v.y, fmaf(T2,m1v.z, fmaf(T3,m1v.w, Pa))));
        float s0 = fmaf(krs_s[tok][0], d0 - kmu_s[tok][0]*Pb, Pc) * scale;
        float s1 = fmaf(krs_s[tok][1], d1 - kmu_s[tok][1]*Pb, Pc) * scale;
        int msk0 = kmask_s[tok][0], msk1 = kmask_s[tok][1];
        float a0, a1;
        if (msk0 && msk1){
            a0=0.f; a1=0.f;
            if (h==0) U_bf[tok*168 + 148] = 0;         // indicator: bothm -> attn_out = 0
        } else {
            if (h==0) U_bf[tok*168 + 148] = 0x3F80;    // bf16(1.0)
            if (msk0)      { a0=0.f; a1=1.f; }
            else if (msk1) { a0=1.f; a1=0.f; }
            else {
                float mx = fmaxf(s0,s1);
                float e0 = __expf(s0-mx), e1 = __expf(s1-mx);
                float inv = 1.f/(e0+e1);
                a0 = e0*inv; a1 = e1*inv;
            }
        }
        int cb = tok*168 + 128 + h*5;
        U_bf[cb+0] = f2bf(fmaf(a0, m0v.x, a1*m1v.x));
        U_bf[cb+1] = f2bf(fmaf(a0, m0v.y, a1*m1v.y));
        U_bf[cb+2] = f2bf(fmaf(a0, m0v.z, a1*m1v.z));
        U_bf[cb+3] = f2bf(fmaf(a0, m0v.w, a1*m1v.w));
        U_bf[cb+4] = f2bf(a0 + a1);
    }
    __syncthreads();

    // ---- phase 3: GEMM C (K=160, attn_out folded) -> leaky -> H1 ----
    {
        bf16x8 bfr[5];
        #pragma unroll
        for (int p=0;p<4;p++) bfr[p] = *(const bf16x8*)&pb[((2*32 + w*4 + p)*64 + l)*8];
        bfr[4] = *(const bf16x8*)&pb[4096 + (w*64 + l)*8];
        f32x4 acc[4];
        #pragma unroll
        for (int tt=0;tt<4;tt++) acc[tt] = (f32x4){0.f,0.f,0.f,0.f};
        #pragma unroll
        for (int p=0;p<5;p++){
            const int ko = p*32 + quad*8;
            #pragma unroll
            for (int tt=0;tt<4;tt++){
                bf16x8 a = *(const bf16x8*)&U_bf[(tt*16+col)*168 + ko];
                acc[tt] = __builtin_amdgcn_mfma_f32_16x16x32_bf16(a, bfr[p], acc[tt], 0,0,0);
            }
        }
        const float b0j = b0[jj];
        #pragma unroll
        for (int tt=0;tt<4;tt++){
            #pragma unroll
            for (int reg=0;reg<4;reg++){
                int tok = tt*16 + quad*4 + reg;
                float v = acc[tt][reg] + b0j;
                v = (v > 0.f) ? v : 0.01f*v;
                H1_bf[tok*136 + jj] = f2bf(v);
            }
        }
    }
    __syncthreads();

    // ---- phase 4: GEMM D -> leaky -> *fcw -> reduce ----
    {
        bf16x8 bfr[4];
        #pragma unroll
        for (int p=0;p<4;p++) bfr[p] = *(const bf16x8*)&pb[((3*32 + w*4 + p)*64 + l)*8];
        f32x4 acc[4];
        #pragma unroll
        for (int tt=0;tt<4;tt++) acc[tt] = (f32x4){0.f,0.f,0.f,0.f};
        #pragma unroll
        for (int p=0;p<4;p++){
            const int ko = p*32 + quad*8;
            #pragma unroll
            for (int tt=0;tt<4;tt++){
                bf16x8 a = *(const bf16x8*)&H1_bf[(tt*16+col)*136 + ko];
                acc[tt] = __builtin_amdgcn_mfma_f32_16x16x32_bf16(a, bfr[p], acc[tt], 0,0,0);
            }
        }
        const float b1j = b1[jj], fcj = fcw[jj];
        float pv[16];
        #pragma unroll
        for (int tt=0;tt<4;tt++){
            #pragma unroll
            for (int reg=0;reg<4;reg++){
                float v = acc[tt][reg] + b1j;
                v = (v > 0.f) ? v : 0.01f*v;
                pv[tt*4+reg] = v * fcj;
            }
        }
        #pragma unroll
        for (int m=1;m<16;m<<=1){
            #pragma unroll
            for (int q2=0;q2<16;q2++) pv[q2] += __shfl_xor(pv[q2], m);
        }
        if (col==0){
            #pragma unroll
            for (int tt=0;tt<4;tt++){
                #pragma unroll
                for (int reg=0;reg<4;reg++)
                    praw[(tt*16 + quad*4 + reg)*8 + w] = pv[tt*4+reg];   // praw reused as part
            }
        }
    }
    __syncthreads();

    // ---- phase 5 ----
    if (t < 64){
        float a = fcb[0];
        #pragma unroll
        for (int k=0;k<8;k++) a += praw[t*8 + k];
        out[n0 + t] = a;
    }
}

extern "C" void kernel_launch(void* const* d_in, const int* in_sizes, int n_in,
                              void* d_out, int out_size, void* d_ws, size_t ws_size,
                              hipStream_t stream) {
    const float* obs       = (const float*)d_in[0];
    const float* h0        = (const float*)d_in[1];
    const float* enc_air_w = (const float*)d_in[2];
    const float* enc_air_b = (const float*)d_in[3];
    const float* enc_m_w   = (const float*)d_in[4];
    const float* enc_m_b   = (const float*)d_in[5];
    const float* gru_wih   = (const float*)d_in[6];
    const float* gru_whh   = (const float*)d_in[7];
    const float* gru_bih   = (const float*)d_in[8];
    const float* gru_bhh   = (const float*)d_in[9];
    const float* qln_w     = (const float*)d_in[10];
    const float* qln_b     = (const float*)d_in[11];
    const float* kln_w     = (const float*)d_in[12];
    const float* kln_b     = (const float*)d_in[13];
    const float* attn_in_w = (const float*)d_in[14];
    const float* attn_in_b = (const float*)d_in[15];
    const float* attn_out_w= (const float*)d_in[16];
    const float* attn_out_b= (const float*)d_in[17];
    const float* mlp0_w    = (const float*)d_in[18];
    const float* mlp0_b    = (const float*)d_in[19];
    const float* mlp1_w    = (const float*)d_in[20];
    const float* mlp1_b    = (const float*)d_in[21];
    const float* fco_w     = (const float*)d_in[22];
    const float* fco_b     = (const float*)d_in[23];
    float* out = (float*)d_out;
    float* ws  = (float*)d_ws;
    float* air = ws + WS_AIR;

    precompute_kernel<<<dim3(384), dim3(256), 0, stream>>>(
        enc_air_w, enc_air_b, enc_m_w, enc_m_b, gru_wih, gru_bih,
        qln_w, qln_b, kln_w, kln_b, attn_in_w, attn_in_b,
        attn_out_w, mlp0_w, mlp1_w, ws);

    pack_gru_kernel<<<dim3(256), dim3(256), 0, stream>>>(gru_whh, ws);
    pack2_kernel<<<dim3(27), dim3(256), 0, stream>>>(attn_out_w, attn_out_b, ws);
    pack3_kernel<<<dim3(16), dim3(256), 0, stream>>>(mlp0_w, ws);

    gru_kernel<<<dim3(256), dim3(512), 0, stream>>>(
        obs, h0, gru_bhh, enc_air_b, ws, air, out);

    attnmlp_kernel<<<dim3(N_/64), dim3(512), 0, stream>>>(
        obs, ws, mlp0_b, mlp1_b, fco_w, fco_b, air, out);
}